// Round 1
// baseline (429.602 us; speedup 1.0000x reference)
//
#include <hip/hip_runtime.h>

#define B_ROWS 1024
#define FEAT   256
#define QSZ    32768
#define SHIFT  1024            // rows dropped from the front of queue
#define QX     (QSZ - B_ROWS)  // 31744: q rows sourced from queue
#define BX     32              // x rows per block
#define BQ     256             // q rows per block
#define KF     16              // K-chunk (features per LDS stage)
#define NCH    (FEAT / KF)     // 16 chunks
#define NQB    (QSZ / BQ)      // 128 q-blocks
#define NXB    (B_ROWS / BX)   // 32 x-blocks

// ---------- top-2 helpers (ordering: smaller m first, ties -> smaller index, matching top_k) ----------
struct Top2 { float m1; int j1; float m2; int j2; };

__device__ __forceinline__ bool better(float ma, int ja, float mb, int jb) {
    return (ma < mb) || (ma == mb && ja < jb);
}

__device__ __forceinline__ void t2_insert(Top2& t, float m, int j) {
    if (better(m, j, t.m1, t.j1)) { t.m2 = t.m1; t.j2 = t.j1; t.m1 = m; t.j1 = j; }
    else if (better(m, j, t.m2, t.j2)) { t.m2 = m; t.j2 = j; }
}

__device__ __forceinline__ void t2_merge(Top2& a, const Top2& b) {
    t2_insert(a, b.m1, b.j1);
    t2_insert(a, b.m2, b.j2);
}

__device__ __forceinline__ float4 t2_pack(const Top2& t) {
    return make_float4(t.m1, __int_as_float(t.j1), t.m2, __int_as_float(t.j2));
}

__device__ __forceinline__ Top2 t2_unpack(float4 v) {
    Top2 t; t.m1 = v.x; t.j1 = __float_as_int(v.y); t.m2 = v.z; t.j2 = __float_as_int(v.w);
    return t;
}

__device__ __forceinline__ const float* q_row_ptr(int j, const float* x, const float* queue) {
    return (j < QX) ? (queue + (size_t)(j + SHIFT) * FEAT) : (x + (size_t)(j - QX) * FEAT);
}

// ---------- kernel 1: q2[j] = |q_j|^2, one wave per row ----------
__global__ __launch_bounds__(256) void q2_kernel(const float* __restrict__ x,
                                                 const float* __restrict__ queue,
                                                 float* __restrict__ q2) {
    int wave = threadIdx.x >> 6;
    int lane = threadIdx.x & 63;
    int j = blockIdx.x * 4 + wave;
    const float4* row = (const float4*)q_row_ptr(j, x, queue);
    float4 v = row[lane];
    float s = v.x * v.x + v.y * v.y + v.z * v.z + v.w * v.w;
#pragma unroll
    for (int off = 32; off; off >>= 1) s += __shfl_xor(s, off, 64);
    if (lane == 0) q2[j] = s;
}

// ---------- kernel 2: main — register-tiled dot products + fused block-level top-2 ----------
__global__ __launch_bounds__(256, 3) void nn_main(const float* __restrict__ x,
                                                  const float* __restrict__ queue,
                                                  const float* __restrict__ q2,
                                                  float4* __restrict__ partials) {
    __shared__ float xs[FEAT * BX];  // 32 KB, f-major: xs[f*32 + row]
    __shared__ float qs[KF * BQ];    // 16 KB, f-major: qs[f*256 + j]

    const int t  = threadIdx.x;
    const int gx = blockIdx.x;  // x tile index
    const int gy = blockIdx.y;  // q tile index

    // ---- load + transpose x tile (rows gx*32..+31) into xs ----
    // task mapping keeps LDS write banks 2-way max: row varies across lanes.
#pragma unroll
    for (int k = 0; k < 8; ++k) {
        int task = t + 256 * k;                       // 2048 tasks = 32 rows * 64 float4
        int row  = (task >> 1) & 31;
        int f4   = ((task >> 6) << 1) | (task & 1);
        float4 v = ((const float4*)(x + (size_t)(gx * BX + row) * FEAT))[f4];
        int fb = f4 * 4;
        xs[(fb + 0) * BX + row] = v.x;
        xs[(fb + 1) * BX + row] = v.y;
        xs[(fb + 2) * BX + row] = v.z;
        xs[(fb + 3) * BX + row] = v.w;
    }

    const int tx = t & 3;   // x sub-tile: rows 8*tx .. 8*tx+7
    const int tq = t >> 2;  // q sub-tile: cols 4*tq .. 4*tq+3

    float acc[8][4];
#pragma unroll
    for (int r = 0; r < 8; ++r)
#pragma unroll
        for (int c = 0; c < 4; ++c) acc[r][c] = 0.0f;

    // ---- q staging task mapping (per thread, fixed across chunks) ----
    // j spans 32 distinct banks per wave -> 2-way (free) LDS writes.
    int pj[4], pf4[4];
    const float4* pptr[4];
#pragma unroll
    for (int k = 0; k < 4; ++k) {
        int j  = ((t >> 1) & 31) + ((t >> 6) << 5) + ((k & 1) << 7);
        int f4 = (t & 1) + ((k >> 1) << 1);
        pj[k] = j; pf4[k] = f4;
        int jg = gy * BQ + j;
        pptr[k] = (const float4*)q_row_ptr(jg, x, queue);
    }

    float4 pre[4];
#pragma unroll
    for (int k = 0; k < 4; ++k) pre[k] = pptr[k][pf4[k]];  // prefetch chunk 0

    for (int fc = 0; fc < NCH; ++fc) {
        __syncthreads();  // everyone done reading qs (previous chunk)
#pragma unroll
        for (int k = 0; k < 4; ++k) {
            int base = (4 * pf4[k]) * BQ + pj[k];
            qs[base]          = pre[k].x;
            qs[base + BQ]     = pre[k].y;
            qs[base + 2 * BQ] = pre[k].z;
            qs[base + 3 * BQ] = pre[k].w;
        }
        __syncthreads();  // qs ready
        if (fc + 1 < NCH) {
#pragma unroll
            for (int k = 0; k < 4; ++k) pre[k] = pptr[k][(fc + 1) * 4 + pf4[k]];
        }
        // ---- compute: per f-step 3x ds_read_b128 + 32 v_fma_f32, zero addr VALU ----
#pragma unroll
        for (int f = 0; f < KF; ++f) {
            int fg = fc * KF + f;
            float4 xv0 = *(const float4*)&xs[fg * BX + 8 * tx];
            float4 xv1 = *(const float4*)&xs[fg * BX + 8 * tx + 4];
            float4 qv  = *(const float4*)&qs[f * BQ + 4 * tq];
            acc[0][0] += xv0.x * qv.x; acc[0][1] += xv0.x * qv.y; acc[0][2] += xv0.x * qv.z; acc[0][3] += xv0.x * qv.w;
            acc[1][0] += xv0.y * qv.x; acc[1][1] += xv0.y * qv.y; acc[1][2] += xv0.y * qv.z; acc[1][3] += xv0.y * qv.w;
            acc[2][0] += xv0.z * qv.x; acc[2][1] += xv0.z * qv.y; acc[2][2] += xv0.z * qv.z; acc[2][3] += xv0.z * qv.w;
            acc[3][0] += xv0.w * qv.x; acc[3][1] += xv0.w * qv.y; acc[3][2] += xv0.w * qv.z; acc[3][3] += xv0.w * qv.w;
            acc[4][0] += xv1.x * qv.x; acc[4][1] += xv1.x * qv.y; acc[4][2] += xv1.x * qv.z; acc[4][3] += xv1.x * qv.w;
            acc[5][0] += xv1.y * qv.x; acc[5][1] += xv1.y * qv.y; acc[5][2] += xv1.y * qv.z; acc[5][3] += xv1.y * qv.w;
            acc[6][0] += xv1.z * qv.x; acc[6][1] += xv1.z * qv.y; acc[6][2] += xv1.z * qv.z; acc[6][3] += xv1.z * qv.w;
            acc[7][0] += xv1.w * qv.x; acc[7][1] += xv1.w * qv.y; acc[7][2] += xv1.w * qv.z; acc[7][3] += xv1.w * qv.w;
        }
    }

    // ---- epilogue: m = q2 - 2*dot, per-thread top2 over 4 cols, reduce block-wide ----
    const int jbase = gy * BQ + 4 * tq;
    float q2v[4];
#pragma unroll
    for (int c = 0; c < 4; ++c) q2v[c] = q2[jbase + c];

    __syncthreads();  // all LDS reads done; reuse xs as reduction scratch
    float4* red = (float4*)xs;  // [32 rows][64 threads]
#pragma unroll
    for (int r = 0; r < 8; ++r) {
        float m0 = q2v[0] - 2.0f * acc[r][0];
        float m1 = q2v[1] - 2.0f * acc[r][1];
        float m2 = q2v[2] - 2.0f * acc[r][2];
        float m3 = q2v[3] - 2.0f * acc[r][3];
        Top2 tp;
        if (better(m1, jbase + 1, m0, jbase + 0)) { tp.m1 = m1; tp.j1 = jbase + 1; tp.m2 = m0; tp.j2 = jbase + 0; }
        else                                      { tp.m1 = m0; tp.j1 = jbase + 0; tp.m2 = m1; tp.j2 = jbase + 1; }
        t2_insert(tp, m2, jbase + 2);
        t2_insert(tp, m3, jbase + 3);
        red[(8 * tx + r) * 64 + tq] = t2_pack(tp);
    }
    __syncthreads();
    float4* red2 = (float4*)qs;  // [32 rows][8]
    {
        int row = t >> 3, s = t & 7;
        const float4* src = &red[row * 64 + s * 8];
        Top2 a = t2_unpack(src[0]);
#pragma unroll
        for (int u = 1; u < 8; ++u) { Top2 b = t2_unpack(src[u]); t2_merge(a, b); }
        red2[row * 8 + s] = t2_pack(a);
    }
    __syncthreads();
    if (t < 32) {
        const float4* src = &red2[t * 8];
        Top2 a = t2_unpack(src[0]);
#pragma unroll
        for (int u = 1; u < 8; ++u) { Top2 b = t2_unpack(src[u]); t2_merge(a, b); }
        partials[(size_t)(gx * BX + t) * NQB + gy] = t2_pack(a);
    }
}

// ---------- kernel 3: merge 128 partials per x-row, gather output row ----------
__global__ __launch_bounds__(64) void nn_finalize(const float* __restrict__ x,
                                                  const float* __restrict__ queue,
                                                  const float4* __restrict__ partials,
                                                  float4* __restrict__ out) {
    int i = blockIdx.x;
    int l = threadIdx.x;  // 0..63
    const float4* p = partials + (size_t)i * NQB;
    Top2 a = t2_unpack(p[l]);
    Top2 b = t2_unpack(p[l + 64]);
    t2_merge(a, b);
#pragma unroll
    for (int off = 32; off; off >>= 1) {
        Top2 o;
        o.m1 = __shfl_xor(a.m1, off, 64);
        o.j1 = __shfl_xor(a.j1, off, 64);
        o.m2 = __shfl_xor(a.m2, off, 64);
        o.j2 = __shfl_xor(a.j2, off, 64);
        t2_merge(a, o);
    }
    int j2 = a.j2;  // second-nearest (nearest is self) — all lanes converged
    const float4* qrow = (const float4*)q_row_ptr(j2, x, queue);
    out[(size_t)i * 64 + l] = qrow[l];
}

extern "C" void kernel_launch(void* const* d_in, const int* in_sizes, int n_in,
                              void* d_out, int out_size, void* d_ws, size_t ws_size,
                              hipStream_t stream) {
    const float* x     = (const float*)d_in[0];
    const float* queue = (const float*)d_in[1];
    float*  q2       = (float*)d_ws;
    float4* partials = (float4*)((char*)d_ws + (size_t)QSZ * sizeof(float));  // 128 KB offset, 2 MB used

    q2_kernel<<<QSZ / 4, 256, 0, stream>>>(x, queue, q2);
    nn_main<<<dim3(NXB, NQB), 256, 0, stream>>>(x, queue, q2, partials);
    nn_finalize<<<B_ROWS, 64, 0, stream>>>(x, queue, partials, (float4*)d_out);
}

// Round 2
// 138.556 us; speedup vs baseline: 3.1006x; 3.1006x over previous
//
#include <hip/hip_runtime.h>
#include <stdint.h>

#define B_ROWS 1024
#define FEAT   256
#define QSZ    32768
#define SHIFT  1024
#define QX     (QSZ - B_ROWS)   // 31744
#define NQB    (QSZ / 128)      // 256 q-blocks of 128

typedef float  v4f __attribute__((ext_vector_type(4)));
typedef short  v8s __attribute__((ext_vector_type(8)));

// ---------- top-2 helpers (smaller m first; ties -> smaller index, matches top_k) ----------
struct Top2 { float m1; int j1; float m2; int j2; };

__device__ __forceinline__ bool better(float ma, int ja, float mb, int jb) {
    return (ma < mb) || (ma == mb && ja < jb);
}
__device__ __forceinline__ void t2_insert(Top2& t, float m, int j) {
    if (better(m, j, t.m1, t.j1)) { t.m2 = t.m1; t.j2 = t.j1; t.m1 = m; t.j1 = j; }
    else if (better(m, j, t.m2, t.j2)) { t.m2 = m; t.j2 = j; }
}
__device__ __forceinline__ void t2_merge(Top2& a, const Top2& b) {
    t2_insert(a, b.m1, b.j1); t2_insert(a, b.m2, b.j2);
}
__device__ __forceinline__ float4 t2_pack(const Top2& t) {
    return make_float4(t.m1, __int_as_float(t.j1), t.m2, __int_as_float(t.j2));
}
__device__ __forceinline__ Top2 t2_unpack(float4 v) {
    Top2 t; t.m1 = v.x; t.j1 = __float_as_int(v.y); t.m2 = v.z; t.j2 = __float_as_int(v.w);
    return t;
}
__device__ __forceinline__ Top2 t2_shfl_xor(const Top2& a, int mask) {
    Top2 o;
    o.m1 = __shfl_xor(a.m1, mask, 64);
    o.j1 = __shfl_xor(a.j1, mask, 64);
    o.m2 = __shfl_xor(a.m2, mask, 64);
    o.j2 = __shfl_xor(a.j2, mask, 64);
    return o;
}

__device__ __forceinline__ const float* q_row_ptr(int j, const float* x, const float* queue) {
    return (j < QX) ? (queue + (size_t)(j + SHIFT) * FEAT) : (x + (size_t)(j - QX) * FEAT);
}

__device__ __forceinline__ unsigned short f2bf(float f) {  // round-to-nearest-even
    uint32_t u = __float_as_uint(f);
    uint32_t r = u + 0x7FFFu + ((u >> 16) & 1u);
    return (unsigned short)(r >> 16);
}

__device__ __forceinline__ void lds_load16(const void* g, void* l) {
    // async global->LDS DMA, 16B/lane; LDS dest = wave-uniform base + lane*16
    __builtin_amdgcn_global_load_lds(
        (const __attribute__((address_space(1))) uint32_t*)g,
        (__attribute__((address_space(3))) uint32_t*)l, 16, 0, 0);
}

// ---------- kernel 1: build q_bf (bf16, row-major, includes x tail) + q2 (f32) ----------
__global__ __launch_bounds__(256) void convert_kernel(const float* __restrict__ x,
                                                      const float* __restrict__ queue,
                                                      unsigned short* __restrict__ q_bf,
                                                      float* __restrict__ q2) {
    int wave = threadIdx.x >> 6, lane = threadIdx.x & 63;
    int j = blockIdx.x * 4 + wave;
    const float4* row = (const float4*)q_row_ptr(j, x, queue);
    float4 v = row[lane];
    float s = v.x * v.x + v.y * v.y + v.z * v.z + v.w * v.w;
#pragma unroll
    for (int off = 32; off; off >>= 1) s += __shfl_xor(s, off, 64);
    if (lane == 0) q2[j] = s;
    ushort4 h;
    h.x = f2bf(v.x); h.y = f2bf(v.y); h.z = f2bf(v.z); h.w = f2bf(v.w);
    ((ushort4*)q_bf)[(size_t)j * 64 + lane] = h;
}

// ---------- kernel 2: bf16 MFMA GEMM (approx m) + fused per-row top-2 ----------
// Block tile 128x128, K=256 in 4 chunks of 64. Swizzled LDS (granule g' = g ^ (row&7))
// so both the lds-DMA staging and frag ds_read_b128 are conflict-free.
__global__ __launch_bounds__(256, 3) void nn_mfma(const unsigned short* __restrict__ q_bf,
                                                  const float* __restrict__ q2,
                                                  float4* __restrict__ partials) {
    __shared__ unsigned short As[128 * 64];  // 16 KB  [row][granule-swizzled k]
    __shared__ unsigned short Bs[128 * 64];  // 16 KB

    const int t    = threadIdx.x;
    const int w    = t >> 6, lane = t & 63;
    const int wm   = w >> 1, wn = w & 1;
    const int quad = lane >> 4, l16 = lane & 15;
    const int gy   = blockIdx.x;  // q tile (N)
    const int gx   = blockIdx.y;  // x tile (M)

    const unsigned short* x_bf = q_bf + (size_t)QX * FEAT;  // A rows = q rows QX..

    v4f acc[4][4];
#pragma unroll
    for (int a = 0; a < 4; ++a)
#pragma unroll
        for (int b = 0; b < 4; ++b) acc[a][b] = (v4f)0.0f;

    const int srow = lane >> 3;                 // row within 8-row group
    const int sg   = (lane & 7) ^ (srow & 7);   // swizzled source granule

    for (int c = 0; c < 4; ++c) {
        __syncthreads();  // previous chunk's frag reads done
#pragma unroll
        for (int kk = 0; kk < 4; ++kk) {
            int row = w * 32 + kk * 8 + srow;
            const unsigned short* ga = x_bf + (size_t)(gx * 128 + row) * FEAT + c * 64 + sg * 8;
            const unsigned short* gb = q_bf + (size_t)(gy * 128 + row) * FEAT + c * 64 + sg * 8;
            lds_load16(ga, &As[(w * 32 + kk * 8) * 64]);
            lds_load16(gb, &Bs[(w * 32 + kk * 8) * 64]);
        }
        __syncthreads();  // staged (compiler drains vmcnt before barrier)
#pragma unroll
        for (int ks = 0; ks < 2; ++ks) {
            v8s fa[4], fb[4];
            const int goff  = (((ks * 4 + quad) ^ (l16 & 7)) << 4);  // swizzled granule byte
            const int abase = (wm * 64 + l16) * 128 + goff;
            const int bbase = (wn * 64 + l16) * 128 + goff;
#pragma unroll
            for (int tm = 0; tm < 4; ++tm)
                fa[tm] = *(const v8s*)((const char*)As + abase + tm * 2048);
#pragma unroll
            for (int tn = 0; tn < 4; ++tn)
                fb[tn] = *(const v8s*)((const char*)Bs + bbase + tn * 2048);
#pragma unroll
            for (int tm = 0; tm < 4; ++tm)
#pragma unroll
                for (int tn = 0; tn < 4; ++tn)
                    acc[tm][tn] = __builtin_amdgcn_mfma_f32_16x16x32_bf16(fa[tm], fb[tn], acc[tm][tn], 0, 0, 0);
        }
    }

    // ---- epilogue: m = q2 - 2*dot; per-row top2 within wave, merge across wn via LDS ----
    float q2v[4]; int jcol[4];
#pragma unroll
    for (int tn = 0; tn < 4; ++tn) {
        jcol[tn] = gy * 128 + wn * 64 + tn * 16 + l16;
        q2v[tn]  = q2[jcol[tn]];
    }

    __syncthreads();                      // all LDS frag reads done
    float4* scratch = (float4*)As;        // [row 0..127][wn 0..1]
#pragma unroll
    for (int tm = 0; tm < 4; ++tm) {
#pragma unroll
        for (int reg = 0; reg < 4; ++reg) {
            float m0 = q2v[0] - 2.0f * acc[tm][0][reg];
            float m1 = q2v[1] - 2.0f * acc[tm][1][reg];
            float m2 = q2v[2] - 2.0f * acc[tm][2][reg];
            float m3 = q2v[3] - 2.0f * acc[tm][3][reg];
            Top2 tp;
            if (better(m1, jcol[1], m0, jcol[0])) { tp.m1 = m1; tp.j1 = jcol[1]; tp.m2 = m0; tp.j2 = jcol[0]; }
            else                                   { tp.m1 = m0; tp.j1 = jcol[0]; tp.m2 = m1; tp.j2 = jcol[1]; }
            t2_insert(tp, m2, jcol[2]);
            t2_insert(tp, m3, jcol[3]);
#pragma unroll
            for (int mask = 1; mask <= 8; mask <<= 1) t2_merge(tp, t2_shfl_xor(tp, mask));
            if (l16 == 0)
                scratch[(wm * 64 + tm * 16 + quad * 4 + reg) * 2 + wn] = t2_pack(tp);
        }
    }
    __syncthreads();
    if (t < 128) {
        Top2 a = t2_unpack(scratch[t * 2]);
        t2_merge(a, t2_unpack(scratch[t * 2 + 1]));
        partials[(size_t)(gx * 128 + t) * NQB + gy] = t2_pack(a);
    }
}

// ---------- kernel 3: margin filter + exact f32 rescore + gather ----------
__global__ __launch_bounds__(256) void nn_finalize(const float* __restrict__ x,
                                                   const float* __restrict__ queue,
                                                   const float* __restrict__ q2,
                                                   const float4* __restrict__ partials,
                                                   float* __restrict__ out) {
    __shared__ float  xs[256];
    __shared__ float4 red[256];
    __shared__ int    list[64];
    __shared__ float  escore[64];
    __shared__ int    s_cnt;
    __shared__ float  s_cut;
    __shared__ int    s_j2;

    const int t = threadIdx.x, i = blockIdx.x;
    const int w = t >> 6, lane = t & 63;

    xs[t] = x[(size_t)i * FEAT + t];
    float4 p = partials[(size_t)i * NQB + t];
    Top2 mine = t2_unpack(p);
    red[t] = p;
    if (t == 0) s_cnt = 0;
    __syncthreads();

    if (w == 0) {  // wave 0: global approx top2 -> cutoff
        Top2 a = t2_unpack(red[lane]);
        t2_merge(a, t2_unpack(red[lane + 64]));
        t2_merge(a, t2_unpack(red[lane + 128]));
        t2_merge(a, t2_unpack(red[lane + 192]));
#pragma unroll
        for (int mask = 1; mask <= 32; mask <<= 1) t2_merge(a, t2_shfl_xor(a, mask));
        if (lane == 0) s_cut = a.m2 + 1.0f;  // ~7 sigma of bf16 scoring noise
    }
    __syncthreads();
    float cut = s_cut;
    if (mine.m1 <= cut) { int q_ = atomicAdd(&s_cnt, 1); if (q_ < 64) list[q_] = mine.j1; }
    if (mine.m2 <= cut) { int q_ = atomicAdd(&s_cnt, 1); if (q_ < 64) list[q_] = mine.j2; }
    __syncthreads();
    int n = min(s_cnt, 64);

    for (int c = w; c < n; c += 4) {  // one candidate per wave, exact f32 rescore
        int j = list[c];
        const float4* qr = (const float4*)q_row_ptr(j, x, queue);
        float4 qv = qr[lane];
        float4 xv = ((const float4*)xs)[lane];
        float s = qv.x * xv.x + qv.y * xv.y + qv.z * xv.z + qv.w * xv.w;
#pragma unroll
        for (int off = 32; off; off >>= 1) s += __shfl_xor(s, off, 64);
        if (lane == 0) escore[c] = q2[j] - 2.0f * s;
    }
    __syncthreads();
    if (t == 0) {
        Top2 a;
        a.m1 = __builtin_inff(); a.j1 = 0x7FFFFFFF;
        a.m2 = __builtin_inff(); a.j2 = 0x7FFFFFFF;
        for (int c = 0; c < n; ++c) t2_insert(a, escore[c], list[c]);
        s_j2 = a.j2;  // second-nearest (nearest is self)
    }
    __syncthreads();
    out[(size_t)i * FEAT + t] = q_row_ptr(s_j2, x, queue)[t];
}

extern "C" void kernel_launch(void* const* d_in, const int* in_sizes, int n_in,
                              void* d_out, int out_size, void* d_ws, size_t ws_size,
                              hipStream_t stream) {
    const float* x     = (const float*)d_in[0];
    const float* queue = (const float*)d_in[1];

    unsigned short* q_bf     = (unsigned short*)d_ws;                      // 16 MB
    float*          q2       = (float*)((char*)d_ws + (16u << 20));        // 128 KB
    float4*         partials = (float4*)((char*)d_ws + (17u << 20));       // 4 MB

    convert_kernel<<<QSZ / 4, 256, 0, stream>>>(x, queue, q_bf, q2);
    nn_mfma<<<dim3(QSZ / 128, B_ROWS / 128), 256, 0, stream>>>(q_bf, q2, partials);
    nn_finalize<<<B_ROWS, 256, 0, stream>>>(x, queue, q2, partials, (float*)d_out);
}

// Round 3
// 111.864 us; speedup vs baseline: 3.8404x; 1.2386x over previous
//
#include <hip/hip_runtime.h>
#include <stdint.h>

#define B_ROWS 1024
#define FEAT   256
#define QSZ    32768
#define SHIFT  1024
#define QX     (QSZ - B_ROWS)   // 31744
#define NQB    256              // q-tiles of 128 (M dim of GEMM)
#define NXB    8                // x-tiles of 128 (N dim)
#define MARGIN 8.0f             // covers bf16 noise (~2) + key quantization (~2.5/side)

typedef float  v4f __attribute__((ext_vector_type(4)));
typedef short  v8s __attribute__((ext_vector_type(8)));

// ---------- packed score keys: orderable(m)[31:15] | j[14:0] ----------
__device__ __forceinline__ uint32_t key_flip(uint32_t u) {
    return u ^ ((uint32_t)((int32_t)u >> 31) | 0x80000000u);
}
__device__ __forceinline__ float key_m(uint32_t k) {  // floor-approx m back from key
    uint32_t u = k & 0xFFFF8000u;
    u = (u & 0x80000000u) ? (u ^ 0x80000000u) : ~u;
    return __uint_as_float(u);
}
// sorted-pair top2 insert / merge (branchless)
__device__ __forceinline__ void k2_insert(uint32_t& k1, uint32_t& k2, uint32_t key) {
    uint32_t hi = max(k1, key); k1 = min(k1, key); k2 = min(k2, hi);
}
__device__ __forceinline__ uint2 k2_merge(uint2 a, uint2 b) {
    uint32_t hi = max(a.x, b.x);
    uint2 r; r.x = min(a.x, b.x); r.y = min(min(a.y, b.y), hi);
    return r;
}

// ---------- exact-score top2 (float + index tie-break, matches top_k) ----------
struct Top2 { float m1; int j1; float m2; int j2; };
__device__ __forceinline__ bool better(float ma, int ja, float mb, int jb) {
    return (ma < mb) || (ma == mb && ja < jb);
}
__device__ __forceinline__ void t2_insert(Top2& t, float m, int j) {
    if (better(m, j, t.m1, t.j1)) { t.m2 = t.m1; t.j2 = t.j1; t.m1 = m; t.j1 = j; }
    else if (better(m, j, t.m2, t.j2)) { t.m2 = m; t.j2 = j; }
}

__device__ __forceinline__ const float* q_row_ptr(int j, const float* x, const float* queue) {
    return (j < QX) ? (queue + (size_t)(j + SHIFT) * FEAT) : (x + (size_t)(j - QX) * FEAT);
}

__device__ __forceinline__ unsigned short f2bf(float f) {  // round-to-nearest-even
    uint32_t u = __float_as_uint(f);
    uint32_t r = u + 0x7FFFu + ((u >> 16) & 1u);
    return (unsigned short)(r >> 16);
}

__device__ __forceinline__ void lds_load16(const void* g, void* l) {
    __builtin_amdgcn_global_load_lds(
        (const __attribute__((address_space(1))) uint32_t*)g,
        (__attribute__((address_space(3))) uint32_t*)l, 16, 0, 0);
}

// ---------- kernel 1: q_bf (bf16 row-major, x tail included) + q2 (f32) ----------
__global__ __launch_bounds__(256) void convert_kernel(const float* __restrict__ x,
                                                      const float* __restrict__ queue,
                                                      unsigned short* __restrict__ q_bf,
                                                      float* __restrict__ q2) {
    int wave = threadIdx.x >> 6, lane = threadIdx.x & 63;
    int j = blockIdx.x * 4 + wave;
    const float4* row = (const float4*)q_row_ptr(j, x, queue);
    float4 v = row[lane];
    float s = v.x * v.x + v.y * v.y + v.z * v.z + v.w * v.w;
#pragma unroll
    for (int off = 32; off; off >>= 1) s += __shfl_xor(s, off, 64);
    if (lane == 0) q2[j] = s;
    ushort4 h;
    h.x = f2bf(v.x); h.y = f2bf(v.y); h.z = f2bf(v.z); h.w = f2bf(v.w);
    ((ushort4*)q_bf)[(size_t)j * 64 + lane] = h;
}

// ---------- kernel 2: MFMA GEMM, A=q rows (M), B=x rows (N); packed-key top2 per x-col ----------
__global__ __launch_bounds__(256, 3) void nn_mfma(const unsigned short* __restrict__ q_bf,
                                                  const float* __restrict__ q2,
                                                  uint2* __restrict__ partials) {
    __shared__ unsigned short As[128 * 64];  // 16 KB, q-tile chunk [row][swizzled k]
    __shared__ unsigned short Bs[128 * 64];  // 16 KB, x-tile chunk
    __shared__ float sq2[128];
    __shared__ uint2 scr[128][2];            // cross-wm merge scratch (2 KB)

    const int t    = threadIdx.x;
    const int w    = t >> 6, lane = t & 63;
    const int wm   = w >> 1, wn = w & 1;
    const int quad = lane >> 4, l16 = lane & 15;
    const int gy   = blockIdx.x;  // q tile (rows of D)
    const int gx   = blockIdx.y;  // x tile (cols of D)

    const unsigned short* x_bf = q_bf + (size_t)QX * FEAT;

    if (t < 128) sq2[t] = q2[gy * 128 + t];

    v4f acc[4][4];  // [tm: q sub-rows][tn: x sub-cols]
#pragma unroll
    for (int a = 0; a < 4; ++a)
#pragma unroll
        for (int b = 0; b < 4; ++b) acc[a][b] = (v4f)0.0f;

    const int srow = lane >> 3;
    const int sg   = (lane & 7) ^ srow;  // swizzled source granule

    for (int c = 0; c < 4; ++c) {
        __syncthreads();
#pragma unroll
        for (int kk = 0; kk < 4; ++kk) {
            int row = w * 32 + kk * 8 + srow;
            const unsigned short* ga = q_bf + (size_t)(gy * 128 + row) * FEAT + c * 64 + sg * 8;
            const unsigned short* gb = x_bf + (size_t)(gx * 128 + row) * FEAT + c * 64 + sg * 8;
            lds_load16(ga, &As[(w * 32 + kk * 8) * 64]);
            lds_load16(gb, &Bs[(w * 32 + kk * 8) * 64]);
        }
        __syncthreads();
#pragma unroll
        for (int ks = 0; ks < 2; ++ks) {
            v8s fa[4], fb[4];
            const int goff  = (((ks * 4 + quad) ^ (l16 & 7)) << 4);
            const int abase = (wm * 64 + l16) * 128 + goff;
            const int bbase = (wn * 64 + l16) * 128 + goff;
#pragma unroll
            for (int tm = 0; tm < 4; ++tm)
                fa[tm] = *(const v8s*)((const char*)As + abase + tm * 2048);
#pragma unroll
            for (int tn = 0; tn < 4; ++tn)
                fb[tn] = *(const v8s*)((const char*)Bs + bbase + tn * 2048);
#pragma unroll
            for (int tm = 0; tm < 4; ++tm)
#pragma unroll
                for (int tn = 0; tn < 4; ++tn)
                    acc[tm][tn] = __builtin_amdgcn_mfma_f32_16x16x32_bf16(fa[tm], fb[tn], acc[tm][tn], 0, 0, 0);
        }
    }

    // ---- epilogue: keys = orderable(q2[row]-2*acc)|row; per-thread top2 per x-col ----
    float q2r[4][4];
#pragma unroll
    for (int tm = 0; tm < 4; ++tm) {
        v4f qq = *(const v4f*)&sq2[wm * 64 + tm * 16 + quad * 4];
#pragma unroll
        for (int r = 0; r < 4; ++r) q2r[tm][r] = qq[r];
    }
    const int jbase = gy * 128 + wm * 64 + quad * 4;

    uint2 best[4];
#pragma unroll
    for (int tn = 0; tn < 4; ++tn) {
        uint32_t k1 = 0xFFFFFFFFu, k2 = 0xFFFFFFFFu;
#pragma unroll
        for (int tm = 0; tm < 4; ++tm)
#pragma unroll
            for (int r = 0; r < 4; ++r) {
                float m = fmaf(-2.0f, acc[tm][tn][r], q2r[tm][r]);
                uint32_t u = key_flip(__float_as_uint(m));
                uint32_t key = (u & 0xFFFF8000u) | (uint32_t)(jbase + tm * 16 + r);
                k2_insert(k1, k2, key);
            }
        // merge across quads (same x-col lives in lanes l16, l16+16, l16+32, l16+48)
#pragma unroll
        for (int mask = 16; mask <= 32; mask <<= 1) {
            uint32_t o1 = __shfl_xor(k1, mask, 64);
            uint32_t o2 = __shfl_xor(k2, mask, 64);
            uint32_t hi = max(k1, o1);
            k1 = min(k1, o1);
            k2 = min(min(k2, o2), hi);
        }
        best[tn] = make_uint2(k1, k2);
    }
    if (quad == 0) {
#pragma unroll
        for (int tn = 0; tn < 4; ++tn) scr[wn * 64 + tn * 16 + l16][wm] = best[tn];
    }
    __syncthreads();
    if (t < 128) {
        uint2 r = k2_merge(scr[t][0], scr[t][1]);
        partials[(size_t)(gx * 128 + t) * NQB + gy] = r;
    }
}

// ---------- kernel 3: key-based cutoff + exact f32 rescore + gather ----------
__global__ __launch_bounds__(256) void nn_finalize(const float* __restrict__ x,
                                                   const float* __restrict__ queue,
                                                   const float* __restrict__ q2,
                                                   const uint2* __restrict__ partials,
                                                   float* __restrict__ out) {
    __shared__ float    xs[256];
    __shared__ uint2    red[256];
    __shared__ int      list[64];
    __shared__ float    escore[64];
    __shared__ int      s_cnt;
    __shared__ uint32_t s_kcut;
    __shared__ int      s_j2;

    const int t = threadIdx.x, i = blockIdx.x;
    const int w = t >> 6, lane = t & 63;

    xs[t] = x[(size_t)i * FEAT + t];
    uint2 p = partials[(size_t)i * NQB + t];
    red[t] = p;
    if (t == 0) s_cnt = 0;
    __syncthreads();

    if (w == 0) {  // approx global top2 (keys) -> cutoff key
        uint2 a = red[lane];
        a = k2_merge(a, red[lane + 64]);
        a = k2_merge(a, red[lane + 128]);
        a = k2_merge(a, red[lane + 192]);
#pragma unroll
        for (int mask = 1; mask <= 32; mask <<= 1) {
            uint2 o;
            o.x = __shfl_xor(a.x, mask, 64);
            o.y = __shfl_xor(a.y, mask, 64);
            a = k2_merge(a, o);
        }
        if (lane == 0) {
            float cutf = key_m(a.y) + MARGIN;
            s_kcut = key_flip(__float_as_uint(cutf)) | 0x7FFFu;
        }
    }
    __syncthreads();
    uint32_t kcut = s_kcut;
    if (p.x <= kcut) { int q_ = atomicAdd(&s_cnt, 1); if (q_ < 64) list[q_] = (int)(p.x & 0x7FFFu); }
    if (p.y <= kcut) { int q_ = atomicAdd(&s_cnt, 1); if (q_ < 64) list[q_] = (int)(p.y & 0x7FFFu); }
    __syncthreads();
    int n = min(s_cnt, 64);

    for (int c = w; c < n; c += 4) {  // exact f32 rescore, one candidate per wave
        int j = list[c];
        const float4* qr = (const float4*)q_row_ptr(j, x, queue);
        float4 qv = qr[lane];
        float4 xv = ((const float4*)xs)[lane];
        float s = qv.x * xv.x + qv.y * xv.y + qv.z * xv.z + qv.w * xv.w;
#pragma unroll
        for (int off = 32; off; off >>= 1) s += __shfl_xor(s, off, 64);
        if (lane == 0) escore[c] = q2[j] - 2.0f * s;
    }
    __syncthreads();
    if (t == 0) {
        Top2 a;
        a.m1 = __builtin_inff(); a.j1 = 0x7FFFFFFF;
        a.m2 = __builtin_inff(); a.j2 = 0x7FFFFFFF;
        for (int c = 0; c < n; ++c) t2_insert(a, escore[c], list[c]);
        s_j2 = a.j2;  // second-nearest (nearest is self)
    }
    __syncthreads();
    out[(size_t)i * FEAT + t] = q_row_ptr(s_j2, x, queue)[t];
}

extern "C" void kernel_launch(void* const* d_in, const int* in_sizes, int n_in,
                              void* d_out, int out_size, void* d_ws, size_t ws_size,
                              hipStream_t stream) {
    const float* x     = (const float*)d_in[0];
    const float* queue = (const float*)d_in[1];

    unsigned short* q_bf     = (unsigned short*)d_ws;                    // 16 MB
    float*          q2       = (float*)((char*)d_ws + (16u << 20));      // 128 KB
    uint2*          partials = (uint2*)((char*)d_ws + (17u << 20));      // 2 MB

    convert_kernel<<<QSZ / 4, 256, 0, stream>>>(x, queue, q_bf, q2);
    nn_mfma<<<dim3(NQB, NXB), 256, 0, stream>>>(q_bf, q2, partials);
    nn_finalize<<<B_ROWS, 256, 0, stream>>>(x, queue, q2, partials, (float*)d_out);
}